// Round 1
// 290.886 us; speedup vs baseline: 1.0248x; 1.0248x over previous
//
#include <hip/hip_runtime.h>
#include <math.h>

// Problem constants (from reference)
#define D_SVG 256
#define N_TYPE 10
#define N_PAR 12
#define F_TOT (D_SVG + N_TYPE + N_PAR)        // 278
#define ROWS_PER_BLOCK 32
#define THREADS 256
#define N4_PER_BLOCK (ROWS_PER_BLOCK * F_TOT / 4)   // 2224 float4 per block
#define N4_ITERS ((N4_PER_BLOCK + THREADS - 1) / THREADS)  // 9 (last partial: 176)

// ws layout:
//   float4   part[4096]   @ 0       (x=svg_sq, y=par12_sq, z=nll, w=par_corr)
//   unsigned bitmap[4096] @ 65536   (bit r = row 32*blk+r valid) -> cnt via popc

// ---------------- Fused kernel: streaming MSE + per-row CE/correction ----------------
// One block = 32 rows. The CE / param-correction gather (formerly meta_kernel, a
// latency-bound 2-blocks/CU kernel) reads ONLY bytes this block streams anyway, so it
// is done in-block: the loads are L1/L2-hot and add zero HBM traffic. This also
// removes the meta->bulk bitmap dependency (full kernel serialization).
__global__ __launch_bounds__(THREADS) void fused_kernel(const float* __restrict__ input,
                                                        const float* __restrict__ target,
                                                        float4* __restrict__ part,
                                                        unsigned* __restrict__ bitmap) {
    __shared__ float sred[4][4];
    const int tid  = threadIdx.x;
    const int lane = tid & 63, wave = tid >> 6;
    const long row0 = (long)blockIdx.x * ROWS_PER_BLOCK;

    // Per-wave valid bitmap of the block's 32 rows (every wave computes the same
    // value -> no shared-mem broadcast / __syncthreads needed; lines are reused by
    // the streaming phase so the probe loads cost no extra HBM).
    bool vld = false;
    if (lane < 32) vld = (target[(row0 + lane) * F_TOT + D_SVG] != -1.0f);
    const unsigned bits = (unsigned)__ballot(vld);

    if (bits == 0u) {   // all 32 rows padded: contribution handled in closed form
        if (tid == 0) { part[blockIdx.x] = make_float4(0.f, 0.f, 0.f, 0.f);
                        bitmap[blockIdx.x] = 0u; }
        return;
    }

    // ---- per-row CE + param correction (threads 0..31, one row each) ----
    float nll = 0.0f, corr = 0.0f;
    if (tid < 32 && ((bits >> tid) & 1u)) {
        const long rb = (row0 + tid) * F_TOT;
        const float2* __restrict__ tg2 = (const float2*)(target + rb + D_SVG);
        const float2* __restrict__ in2 = (const float2*)(input  + rb + D_SVG);
        float tt[N_TYPE], l[N_TYPE];
        #pragma unroll
        for (int j = 0; j < 5; ++j) { float2 v = tg2[j]; tt[2*j] = v.x; tt[2*j+1] = v.y; }
        #pragma unroll
        for (int j = 0; j < 5; ++j) { float2 v = in2[j]; l[2*j]  = v.x; l[2*j+1]  = v.y; }
        int ti = 0; float best = tt[0];
        #pragma unroll
        for (int j = 1; j < N_TYPE; ++j) { if (tt[j] > best) { best = tt[j]; ti = j; } }
        float m = l[0];
        #pragma unroll
        for (int j = 1; j < N_TYPE; ++j) m = fmaxf(m, l[j]);
        float s = 0.0f;
        #pragma unroll
        for (int j = 0; j < N_TYPE; ++j) s += __expf(l[j] - m);
        nll = __logf(s) + m - l[ti];
        // replaced params {ti, ti+1, ti+2} (ti<=9, no wrap) contribute 0 in the
        // reference; the bulk sum covers all 12 -> record the subtraction.
        const long p = rb + (D_SVG + N_TYPE) + ti;
        float d0 = input[p]     - target[p];
        float d1 = input[p + 1] - target[p + 1];
        float d2 = input[p + 2] - target[p + 2];
        corr = d0 * d0 + d1 * d1 + d2 * d2;
    }

    // ---- streaming masked MSE over the block's 32 rows ----
    // Padding is suffix-contiguous per batch and 512 % 32 == 0 (blocks never cross a
    // batch), so bits is a prefix mask: bound the loop at the last valid row. The
    // per-element validity check is KEPT, so correctness never depends on this.
    const unsigned k   = (unsigned)__popc(bits);
    const unsigned pre = (k == 32u) ? 0xffffffffu : ((1u << k) - 1u);
    const unsigned n4v = (bits == pre) ? ((k * (unsigned)F_TOT + 3u) >> 2)
                                       : (unsigned)N4_PER_BLOCK;

    const float4* __restrict__ in4p = (const float4*)(input  + row0 * F_TOT);
    const float4* __restrict__ tg4p = (const float4*)(target + row0 * F_TOT);

    float svg = 0.0f, par = 0.0f;

    // 278 % 4 == 2: a float4 crosses a row boundary only between elems 1|2.
    auto accum = [&](unsigned idx, float4 ivv, float4 tvv) {
        unsigned e0 = idx * 4u;
        unsigned ra = e0 / (unsigned)F_TOT;            // compiler magic-mul
        unsigned rb = (e0 + 2u) / (unsigned)F_TOT;
        unsigned fa = e0 - ra * (unsigned)F_TOT;
        unsigned fb = (e0 + 2u) - rb * (unsigned)F_TOT;
        unsigned vA = (bits >> ra) & 1u;
        unsigned vB = (bits >> rb) & 1u;
        float xs[4] = {ivv.x, ivv.y, ivv.z, ivv.w};
        float ts[4] = {tvv.x, tvv.y, tvv.z, tvv.w};
        #pragma unroll
        for (int j = 0; j < 4; ++j) {
            unsigned v    = (j < 2) ? vA : vB;
            unsigned feat = ((j < 2) ? fa : fb) + (unsigned)(j & 1);
            float d = xs[j] - ts[j];
            float sq = d * d;
            svg += (v && feat < D_SVG) ? sq : 0.0f;
            par += (v && feat >= D_SVG + N_TYPE) ? sq : 0.0f;
        }
    };

    float4 iv[N4_ITERS], tv[N4_ITERS];
    #pragma unroll
    for (int u = 0; u < N4_ITERS; ++u) {
        unsigned idx = (unsigned)tid + u * THREADS;
        if (idx < n4v) { iv[u] = in4p[idx]; tv[u] = tg4p[idx]; }
    }
    #pragma unroll
    for (int u = 0; u < N4_ITERS; ++u) {
        unsigned idx = (unsigned)tid + u * THREADS;
        if (idx < n4v) accum(idx, iv[u], tv[u]);
    }

    // ---- block reduce (svg, par, nll, corr) ----
    float vals[4] = {svg, par, nll, corr};
    #pragma unroll
    for (int v = 0; v < 4; ++v) {
        float x = vals[v];
        #pragma unroll
        for (int off = 32; off > 0; off >>= 1) x += __shfl_down(x, off, 64);
        vals[v] = x;
    }
    if (lane == 0) {
        #pragma unroll
        for (int v = 0; v < 4; ++v) sred[wave][v] = vals[v];
    }
    __syncthreads();
    if (tid == 0) {
        float s0 = sred[0][0] + sred[1][0] + sred[2][0] + sred[3][0];
        float s1 = sred[0][1] + sred[1][1] + sred[2][1] + sred[3][1];
        float s2 = sred[0][2] + sred[1][2] + sred[2][2] + sred[3][2];
        float s3 = sred[0][3] + sred[1][3] + sred[2][3] + sred[3][3];
        part[blockIdx.x]   = make_float4(s0, s1, s2, s3);
        bitmap[blockIdx.x] = bits;
    }
}

// ---------------- Final reduce + loss composition ----------------
__global__ __launch_bounds__(256) void loss_final(const float4* __restrict__ part,
                                                  const unsigned* __restrict__ bitmap,
                                                  float* __restrict__ out,
                                                  int nb, int nrows) {
    __shared__ double sred[4][5];
    const int tid = threadIdx.x;
    double svg = 0.0, par = 0.0, nll = 0.0, corr = 0.0, cnt = 0.0;
    for (int i = tid; i < nb; i += 256) {
        float4 v = part[i];
        svg += v.x; par += v.y; nll += v.z; corr += v.w;
        cnt += (double)__popc(bitmap[i]);
    }
    double vals[5] = {svg, par, nll, corr, cnt};
    #pragma unroll
    for (int v = 0; v < 5; ++v) {
        double x = vals[v];
        #pragma unroll
        for (int off = 32; off > 0; off >>= 1) x += __shfl_down(x, off, 64);
        vals[v] = x;
    }
    const int wave = tid >> 6, lane = tid & 63;
    if (lane == 0) {
        #pragma unroll
        for (int v = 0; v < 5; ++v) sred[wave][v] = vals[v];
    }
    __syncthreads();
    if (tid == 0) {
        double S[5];
        #pragma unroll
        for (int v = 0; v < 5; ++v)
            S[v] = sred[0][v] + sred[1][v] + sred[2][v] + sred[3][v];
        double npad = (double)nrows - S[4];
        // padded rows: every svg/par element contributes (-100-(-1))^2 = 9801
        double svg_t = S[0] + 9801.0 * D_SVG * npad;
        double par_t = S[1] - S[3] + 9801.0 * N_PAR * npad;
        double loss = 10.0 * svg_t / ((double)nrows * D_SVG)
                    + 0.1  * S[2] / fmax(S[4], 1.0)
                    + 1.0  * par_t / ((double)nrows * N_PAR);
        out[0] = (float)loss;
    }
}

extern "C" void kernel_launch(void* const* d_in, const int* in_sizes, int n_in,
                              void* d_out, int out_size, void* d_ws, size_t ws_size,
                              hipStream_t stream) {
    const float* input  = (const float*)d_in[0];
    const float* target = (const float*)d_in[1];
    // d_in[2] (padding mask) unused: padded <=> target[row*278+256] == -1.0f
    float* out = (float*)d_out;

    const int nrows = in_sizes[0] / F_TOT;      // 131072 (divisible by 32)
    const int blk   = nrows / ROWS_PER_BLOCK;   // 4096

    float4*   part   = (float4*)d_ws;
    unsigned* bitmap = (unsigned*)((char*)d_ws + (size_t)blk * sizeof(float4));

    fused_kernel<<<blk, THREADS, 0, stream>>>(input, target, part, bitmap);
    loss_final<<<1, 256, 0, stream>>>(part, bitmap, out, blk, nrows);
}